// Round 1
// baseline (140.212 us; speedup 1.0000x reference)
//
#include <hip/hip_runtime.h>

#define PI_F 3.14159265358979323846f

// ---------------- K1: conv1 7x7 (4->8) + maxpool 2x2 + bias + relu ----------------
// x:(8,4,128,128,8)  w1:(8,4,7,7,1)  b1:(8)  ->  h1:(8,8,61,61,8)
__global__ __launch_bounds__(256) void k_conv1(const float* __restrict__ x,
                                               const float* __restrict__ w1,
                                               const float* __restrict__ b1,
                                               float* __restrict__ h1) {
    const int b = blockIdx.y;
    const int tile = blockIdx.x;              // 64 tiles, 8x8 pooled outputs each
    const int ty = tile >> 3, tx = tile & 7;
    const int py0 = ty * 8, px0 = tx * 8;     // pooled origin
    const int iy0 = py0 * 2, ix0 = px0 * 2;   // conv/input origin

    __shared__ float wts[4][49][8];           // [ic][tap][oc]
    __shared__ float bia[8];
    __shared__ float tin[22][22][8];

    const int tid = threadIdx.x;
    for (int idx = tid; idx < 8 * 4 * 49; idx += 256) {
        int oc = idx / 196, rem = idx % 196;
        int ic = rem / 49, tap = rem % 49;
        wts[ic][tap][oc] = w1[idx];
    }
    if (tid < 8) bia[tid] = b1[tid];

    const int posIdx = tid >> 2, q = tid & 3; // quad q = 2x2 conv positions of one pooled pos
    const int pl = posIdx >> 3, pj = posIdx & 7;
    const int cy = 2 * pl + (q >> 1);
    const int cx = 2 * pj + (q & 1);

    float acc[8][8];
#pragma unroll
    for (int oc = 0; oc < 8; ++oc)
#pragma unroll
        for (int w = 0; w < 8; ++w) acc[oc][w] = 0.f;

    const bool fastCols = (ix0 + 21 < 128);
    for (int ic = 0; ic < 4; ++ic) {
        __syncthreads();
        const float* xb = x + ((size_t)(b * 4 + ic)) * (128 * 128 * 8);
        for (int idx = tid; idx < 968; idx += 256) {   // 22 rows * 44 float4
            int r = idx / 44, c4 = idx % 44;
            int row = iy0 + r;
            float4 v;
            if (fastCols && row < 128) {
                v = *reinterpret_cast<const float4*>(xb + ((size_t)row * 128 + ix0) * 8 + c4 * 4);
            } else {
                float tmp[4];
#pragma unroll
                for (int e = 0; e < 4; ++e) {
                    int off = c4 * 4 + e;
                    int col = ix0 + (off >> 3);
                    int k = off & 7;
                    tmp[e] = (row < 128 && col < 128)
                                 ? xb[((size_t)row * 128 + col) * 8 + k] : 0.f;
                }
                v = make_float4(tmp[0], tmp[1], tmp[2], tmp[3]);
            }
            *reinterpret_cast<float4*>(&tin[0][0][0] + idx * 4) = v;
        }
        __syncthreads();
        for (int kd = 0; kd < 7; ++kd) {
#pragma unroll
            for (int kh = 0; kh < 7; ++kh) {
                const float4* vp = reinterpret_cast<const float4*>(&tin[cy + kd][cx + kh][0]);
                float4 va = vp[0], vb = vp[1];
                const float4* wp = reinterpret_cast<const float4*>(&wts[ic][kd * 7 + kh][0]);
                float4 wa = wp[0], wb = wp[1];
                float vv[8] = {va.x, va.y, va.z, va.w, vb.x, vb.y, vb.z, vb.w};
                float ww[8] = {wa.x, wa.y, wa.z, wa.w, wb.x, wb.y, wb.z, wb.w};
#pragma unroll
                for (int oc = 0; oc < 8; ++oc)
#pragma unroll
                    for (int w = 0; w < 8; ++w)
                        acc[oc][w] = fmaf(ww[oc], vv[w], acc[oc][w]);
            }
        }
    }

    const int pi = py0 + pl, pjg = px0 + pj;
    const bool doStore = (q == 0) && (pi < 61) && (pjg < 61);
#pragma unroll
    for (int oc = 0; oc < 8; ++oc) {
        float vals[8];
#pragma unroll
        for (int w = 0; w < 8; ++w) {
            float m = acc[oc][w];
            m = fmaxf(m, __shfl_xor(m, 1));
            m = fmaxf(m, __shfl_xor(m, 2));
            vals[w] = fmaxf(m + bia[oc], 0.f);
        }
        if (doStore) {
            float4* dst = reinterpret_cast<float4*>(
                h1 + ((((size_t)b * 8 + oc) * 61 + pi) * 61 + pjg) * 8);
            dst[0] = make_float4(vals[0], vals[1], vals[2], vals[3]);
            dst[1] = make_float4(vals[4], vals[5], vals[6], vals[7]);
        }
    }
}

// ---------------- K2: conv2 5x5 (8->10) + maxpool 2x2 + bias + relu ----------------
// h1:(8,8,61,61,8)  w2:(10,8,5,5,1)  b2:(10)  ->  h2:(8,10,28,28,8)
__global__ __launch_bounds__(256) void k_conv2(const float* __restrict__ h1,
                                               const float* __restrict__ w2,
                                               const float* __restrict__ b2,
                                               float* __restrict__ h2) {
    const int b = blockIdx.y;
    const int tile = blockIdx.x;              // 16 tiles, 7x7 pooled each
    const int ty = tile >> 2, tx = tile & 3;
    const int py0 = ty * 7, px0 = tx * 7;
    const int iy0 = py0 * 2, ix0 = px0 * 2;

    __shared__ float wts[8][25][12];          // [ic][tap][oc, padded to 12]
    __shared__ float bia[10];
    __shared__ float tin[18][18][8];

    const int tid = threadIdx.x;
    for (int idx = tid; idx < 2000; idx += 256) {
        int oc = idx / 200, rem = idx % 200;
        int ic = rem / 25, tap = rem % 25;
        wts[ic][tap][oc] = w2[idx];
    }
    for (int idx = tid; idx < 8 * 25 * 2; idx += 256) {
        int ic = idx / 50, rem = idx % 50;
        wts[ic][rem >> 1][10 + (rem & 1)] = 0.f;
    }
    if (tid < 10) bia[tid] = b2[tid];

    int posIdx = tid >> 2;
    const int q = tid & 3;
    const bool active = (tid < 196);
    if (posIdx > 48) posIdx = 48;             // clamp inactive quads (no store)
    const int pl = posIdx / 7, pj = posIdx % 7;
    const int cy = 2 * pl + (q >> 1);
    const int cx = 2 * pj + (q & 1);

    float acc[10][8];
#pragma unroll
    for (int oc = 0; oc < 10; ++oc)
#pragma unroll
        for (int w = 0; w < 8; ++w) acc[oc][w] = 0.f;

    for (int ic = 0; ic < 8; ++ic) {
        __syncthreads();
        const float* hb = h1 + ((size_t)(b * 8 + ic)) * (61 * 61 * 8);
        for (int idx = tid; idx < 648; idx += 256) {  // 18 rows * 36 float4 (all in-bounds)
            int r = idx / 36, c4 = idx % 36;
            float4 v = *reinterpret_cast<const float4*>(
                hb + ((size_t)(iy0 + r) * 61 + ix0) * 8 + c4 * 4);
            *reinterpret_cast<float4*>(&tin[0][0][0] + idx * 4) = v;
        }
        __syncthreads();
        for (int kd = 0; kd < 5; ++kd) {
#pragma unroll
            for (int kh = 0; kh < 5; ++kh) {
                const float4* vp = reinterpret_cast<const float4*>(&tin[cy + kd][cx + kh][0]);
                float4 va = vp[0], vb = vp[1];
                const float4* wp = reinterpret_cast<const float4*>(&wts[ic][kd * 5 + kh][0]);
                float4 wa = wp[0], wb = wp[1], wc = wp[2];
                float vv[8] = {va.x, va.y, va.z, va.w, vb.x, vb.y, vb.z, vb.w};
                float ww[10] = {wa.x, wa.y, wa.z, wa.w, wb.x, wb.y, wb.z, wb.w, wc.x, wc.y};
#pragma unroll
                for (int oc = 0; oc < 10; ++oc)
#pragma unroll
                    for (int w = 0; w < 8; ++w)
                        acc[oc][w] = fmaf(ww[oc], vv[w], acc[oc][w]);
            }
        }
    }

    const int pi = py0 + pl, pjg = px0 + pj;  // always < 28 for active threads
    const bool doStore = active && (q == 0);
#pragma unroll
    for (int oc = 0; oc < 10; ++oc) {
        float vals[8];
#pragma unroll
        for (int w = 0; w < 8; ++w) {
            float m = acc[oc][w];
            m = fmaxf(m, __shfl_xor(m, 1));
            m = fmaxf(m, __shfl_xor(m, 2));
            vals[w] = fmaxf(m + bia[oc], 0.f);
        }
        if (doStore) {
            float4* dst = reinterpret_cast<float4*>(
                h2 + ((((size_t)b * 10 + oc) * 28 + pi) * 28 + pjg) * 8);
            dst[0] = make_float4(vals[0], vals[1], vals[2], vals[3]);
            dst[1] = make_float4(vals[4], vals[5], vals[6], vals[7]);
        }
    }
}

// ---------------- K3: fc1 (62720 -> 32) + relu ----------------
__global__ __launch_bounds__(256) void k_fc1(const float* __restrict__ feat,
                                             const float* __restrict__ w,
                                             const float* __restrict__ bias,
                                             float* __restrict__ out) {
    const int b = blockIdx.x >> 5, j = blockIdx.x & 31;
    const float4* f4 = reinterpret_cast<const float4*>(feat + (size_t)b * 62720);
    const float4* w4 = reinterpret_cast<const float4*>(w + (size_t)j * 62720);
    float s = 0.f;
    for (int i = threadIdx.x; i < 15680; i += 256) {
        float4 a = f4[i], c = w4[i];
        s = fmaf(a.x, c.x, s);
        s = fmaf(a.y, c.y, s);
        s = fmaf(a.z, c.z, s);
        s = fmaf(a.w, c.w, s);
    }
#pragma unroll
    for (int off = 32; off > 0; off >>= 1) s += __shfl_down(s, off);
    __shared__ float red[4];
    if ((threadIdx.x & 63) == 0) red[threadIdx.x >> 6] = s;
    __syncthreads();
    if (threadIdx.x == 0) {
        float t = red[0] + red[1] + red[2] + red[3] + bias[j];
        out[b * 32 + j] = fmaxf(t, 0.f);
    }
}

// ---------------- K4: fc2 (32 -> 48) + tanh + rigid transform packing ----------------
// rt[(b*8+t)*8] = {R00, R10, R20, T0, R01, R11, R21, T1}
__global__ void k_fc2_rt(const float* __restrict__ fo,
                         const float* __restrict__ w,
                         const float* __restrict__ bias,
                         float* __restrict__ rt) {
    const int tid = threadIdx.x;
    if (tid >= 64) return;
    const int b = tid >> 3, t = tid & 7;
    const float* f = fo + b * 32;
    float th[6];
#pragma unroll
    for (int i = 0; i < 6; ++i) {
        const int o = t * 6 + i;
        float s = bias[o];
        const float* wr = w + o * 32;
#pragma unroll
        for (int k = 0; k < 32; ++k) s = fmaf(f[k], wr[k], s);
        th[i] = tanhf(s);
    }
    float s0, c0, s1, c1, s2, c2;
    sincosf(PI_F * th[0], &s0, &c0);
    sincosf(PI_F * th[1], &s1, &c1);
    sincosf(PI_F * th[2], &s2, &c2);
    const float R00 = c0 * c1, R10 = s0 * c1, R20 = -s1;
    const float R01 = -s0 * c2 + c0 * s1 * s2;
    const float R11 =  c0 * c2 + s0 * s1 * s2;
    const float R21 =  c1 * s2;
    const float T0 = th[3] * 128.f + 64.f - (64.f * R00 + 64.f * R10 + 4.f * R20);
    const float T1 = th[4] * 128.f + 64.f - (64.f * R01 + 64.f * R11 + 4.f * R21);
    float* o = rt + tid * 8;
    o[0] = R00; o[1] = R10; o[2] = R20; o[3] = T0;
    o[4] = R01; o[5] = R11; o[6] = R21; o[7] = T1;
}

// ---------------- K5: flow field + grid output + trilinear grid-sample (fused) ----------------
__global__ __launch_bounds__(256) void k_flow_sample(const float* __restrict__ x,
                                                     const float* __restrict__ rt,
                                                     float* __restrict__ outXt,
                                                     float* __restrict__ outGrid) {
    const int b = blockIdx.y;
    const int l = blockIdx.x * 256 + threadIdx.x;   // voxel index, 131072 per batch
    __shared__ float srt[64];
    if (threadIdx.x < 64) srt[threadIdx.x] = rt[b * 64 + threadIdx.x];
    __syncthreads();

    const float gi = (float)(l >> 10);
    const float gj = (float)((l >> 3) & 127);
    const float gk = (float)(l & 7);

    const float tsx[8] = {32.f, 32.f, 96.f, 96.f, 32.f, 96.f, 64.f, 64.f};
    const float tsy[8] = {32.f, 96.f, 32.f, 96.f, 64.f, 64.f, 32.f, 96.f};

    float u0 = 0.f, u1 = 0.f, es = 0.f;
#pragma unroll
    for (int t = 0; t < 8; ++t) {
        float dx = gi - tsx[t], dy = gj - tsy[t], dz = gk - 4.f;
        float d = sqrtf(dx * dx + dy * dy + dz * dz);
        float e = expf(-d / 10.f);
        const float4 ra = *reinterpret_cast<const float4*>(&srt[t * 8]);
        const float4 rb = *reinterpret_cast<const float4*>(&srt[t * 8 + 4]);
        float f0 = fmaf(gi, ra.x, fmaf(gj, ra.y, fmaf(gk, ra.z, ra.w)));
        float f1 = fmaf(gi, rb.x, fmaf(gj, rb.y, fmaf(gk, rb.z, rb.w)));
        u0 = fmaf(e, f0, u0);
        u1 = fmaf(e, f1, u1);
        es += e;
    }
    const float inv = 1.f / es;
    const float fs0 = u0 * inv, fs1 = u1 * inv;
    const float nf0 = fs0 * (1.f / 64.f) - 1.f;
    const float nf1 = fs1 * (1.f / 64.f) - 1.f;

    float* g = outGrid + ((size_t)b * 131072 + l) * 3;
    g[0] = 0.f; g[1] = nf1; g[2] = nf0;

    // trilinear sample of x[b] at (iz, iy, ix=3.5); x-weights are 0.5/0.5 at x=3,4
    const float iz = fs0 - 0.5f, iy = fs1 - 0.5f;
    const float z0f = floorf(iz), y0f = floorf(iy);
    const float fz = iz - z0f, fy = iy - y0f;
    const int z0 = (int)z0f, y0 = (int)y0f;
    float s0 = 0.f, s1 = 0.f, s2 = 0.f, s3 = 0.f;
    const float* xb = x + (size_t)b * 4 * 131072;
#pragma unroll
    for (int dz = 0; dz < 2; ++dz) {
        const int zc = z0 + dz;
        if (zc < 0 || zc > 127) continue;
        const float wz = dz ? fz : 1.f - fz;
#pragma unroll
        for (int dy = 0; dy < 2; ++dy) {
            const int yc = y0 + dy;
            if (yc < 0 || yc > 127) continue;
            const float wv = wz * (dy ? fy : 1.f - fy) * 0.5f;
            const float* p = xb + ((size_t)zc * 128 + yc) * 8 + 3;
            s0 = fmaf(wv, p[0] + p[1], s0);
            s1 = fmaf(wv, p[131072] + p[131073], s1);
            s2 = fmaf(wv, p[262144] + p[262145], s2);
            s3 = fmaf(wv, p[393216] + p[393217], s3);
        }
    }
    float* o = outXt + (size_t)b * 4 * 131072 + l;
    o[0] = s0; o[131072] = s1; o[262144] = s2; o[393216] = s3;
}

// ---------------- K6: moved + reg ----------------
__global__ void k_moved(const float* __restrict__ pos,
                        const float* __restrict__ centers,
                        const float* __restrict__ gridOut,
                        float* __restrict__ movedOut,
                        float* __restrict__ regOut) {
    const int b = blockIdx.x;
    const int tid = threadIdx.x;
    float nrm = 0.f;
    if (tid < 100) {
        const float* p = pos + ((size_t)b * 100 + tid) * 3;
        float p0 = p[0], p1 = p[1], p2 = p[2];
        int i0 = (int)rintf(p0); i0 = i0 < 0 ? 0 : (i0 > 127 ? 127 : i0);
        int i1 = (int)rintf(p1); i1 = i1 < 0 ? 0 : (i1 > 127 ? 127 : i1);
        int i2 = (int)rintf(p2); i2 = i2 < 0 ? 0 : (i2 > 7 ? 7 : i2);
        size_t l = ((size_t)i0 * 128 + i1) * 8 + i2;
        const float* gp = gridOut + ((size_t)b * 131072 + l) * 3;
        float a0 = gp[2];   // gridback[...,0] = nf0
        float a1 = gp[1];   // gridback[...,1] = nf1
        float m0 = 2.f * p0 - (0.5f + 0.5f * a0) * 127.f;
        float m1 = 2.f * p1 - (0.5f + 0.5f * a1) * 127.f;
        float m2 = 2.f * p2 - 3.5f;   // gridback[...,2] = 0
        float* mo = movedOut + ((size_t)b * 100 + tid) * 3;
        mo[0] = m0; mo[1] = m1; mo[2] = m2;
        const float* ce = centers + tid * 3;
        float d0 = m0 - ce[0], d1 = m1 - ce[1], d2 = m2 - ce[2];
        nrm = sqrtf(d0 * d0 + d1 * d1 + d2 * d2);
    }
    __shared__ float red[128];
    red[tid] = nrm;
    __syncthreads();
    for (int s = 64; s > 0; s >>= 1) {
        if (tid < s) red[tid] += red[tid + s];
        __syncthreads();
    }
    if (tid == 0) regOut[b] = red[0] / 100.f;
}

// ---------------- launch ----------------
extern "C" void kernel_launch(void* const* d_in, const int* in_sizes, int n_in,
                              void* d_out, int out_size, void* d_ws, size_t ws_size,
                              hipStream_t stream) {
    const float* x       = (const float*)d_in[0];
    const float* pos     = (const float*)d_in[1];
    const float* centers = (const float*)d_in[2];
    const float* c1w     = (const float*)d_in[3];
    const float* c1b     = (const float*)d_in[4];
    const float* c2w     = (const float*)d_in[5];
    const float* c2b     = (const float*)d_in[6];
    const float* f1w     = (const float*)d_in[7];
    const float* f1b     = (const float*)d_in[8];
    const float* f2w     = (const float*)d_in[9];
    const float* f2b     = (const float*)d_in[10];

    float* out = (float*)d_out;
    float* ws  = (float*)d_ws;

    // workspace layout (floats)
    float* h1 = ws;                      // 8*8*61*61*8   = 1,905,152
    float* h2 = h1 + 1905152;            // 8*10*28*28*8  =   501,760
    float* fo = h2 + 501760;             // 8*32          =       256
    float* rt = fo + 256;                // 8*8*8         =       512

    // output layout (floats): X_t | grid | reg | moved
    float* outXt    = out;                         // 4,194,304
    float* outGrid  = out + 4194304;               // 3,145,728
    float* outReg   = out + 4194304 + 3145728;     // 8
    float* outMoved = outReg + 8;                  // 2,400

    k_conv1<<<dim3(64, 8), 256, 0, stream>>>(x, c1w, c1b, h1);
    k_conv2<<<dim3(16, 8), 256, 0, stream>>>(h1, c2w, c2b, h2);
    k_fc1<<<256, 256, 0, stream>>>(h2, f1w, f1b, fo);
    k_fc2_rt<<<1, 64, 0, stream>>>(fo, f2w, f2b, rt);
    k_flow_sample<<<dim3(512, 8), 256, 0, stream>>>(x, rt, outXt, outGrid);
    k_moved<<<8, 128, 0, stream>>>(pos, centers, outGrid, outMoved, outReg);
}

// Round 2
// 128.889 us; speedup vs baseline: 1.0879x; 1.0879x over previous
//
#include <hip/hip_runtime.h>

#define PI_F 3.14159265358979323846f

// ---------------- K0: prep — transpose weights for SMEM-uniform access, zero fc1 accum ----
// wt1: [ic(4)][tap(49)][oc(8)] = 1568 floats
// wt2: [ic(8)][tap(25)][oc(12, padded)] = 2400 floats
__global__ void k_prep(const float* __restrict__ w1, const float* __restrict__ w2,
                       float* __restrict__ wt1, float* __restrict__ wt2,
                       float* __restrict__ fo) {
    const int tid = threadIdx.x;
    for (int i = tid; i < 2400; i += 256) wt2[i] = 0.f;
    if (tid < 256) fo[tid] = 0.f;
    __syncthreads();
    for (int i = tid; i < 1568; i += 256) {
        int oc = i / 196, rem = i % 196, ic = rem / 49, tap = rem % 49;
        wt1[(ic * 49 + tap) * 8 + oc] = w1[i];
    }
    for (int i = tid; i < 2000; i += 256) {
        int oc = i / 200, rem = i % 200, ic = rem / 25, tap = rem % 25;
        wt2[(ic * 25 + tap) * 12 + oc] = w2[i];
    }
}

// ---------------- K1: conv1 7x7 (4->8) + maxpool 2x2 + bias + relu ----------------
// x:(8,4,128,128,8) -> h1:(8,8,61,61,8).  Tile: 4x4 pooled.  thread=(pos16,quad4,wq4)
__global__ __launch_bounds__(256, 8) void k_conv1(const float* __restrict__ x,
                                                  const float* __restrict__ wt1,
                                                  const float* __restrict__ b1,
                                                  float* __restrict__ h1) {
    const int b = blockIdx.y;
    const int ty = blockIdx.x >> 4, tx = blockIdx.x & 15;   // 16x16 tiles
    const int py0 = ty * 4, px0 = tx * 4;
    const int iy0 = py0 * 2, ix0 = px0 * 2;

    __shared__ float tin[14 * 14 * 8];   // 6272 B

    const int tid = threadIdx.x;
    const int wq = tid & 3;              // w quarter (2 w each)
    const int cp = (tid >> 2) & 3;       // conv position within 2x2 pool window
    const int pp = tid >> 4;             // pooled position 0..15 (4x4)
    const int pl = pp >> 2, pj = pp & 3;
    const int cy = 2 * pl + (cp >> 1), cx = 2 * pj + (cp & 1);

    float acc[8][2];
#pragma unroll
    for (int oc = 0; oc < 8; ++oc) { acc[oc][0] = 0.f; acc[oc][1] = 0.f; }

    for (int ic = 0; ic < 4; ++ic) {
        __syncthreads();
        const float* xb = x + (size_t)(b * 4 + ic) * 131072;
        for (int idx = tid; idx < 392; idx += 256) {      // 14 rows * 28 float4
            int r = idx / 28, c4 = idx % 28;
            int row = iy0 + r, col = ix0 + (c4 >> 1);
            float4 v = make_float4(0.f, 0.f, 0.f, 0.f);
            if (row < 128 && col < 128)
                v = *reinterpret_cast<const float4*>(xb + ((size_t)row * 128 + col) * 8 + (c4 & 1) * 4);
            *reinterpret_cast<float4*>(&tin[idx * 4]) = v;
        }
        __syncthreads();
        const float* wp = wt1 + ic * 49 * 8;
        for (int kd = 0; kd < 7; ++kd) {
            const float* trow = &tin[((cy + kd) * 14 + cx) * 8 + wq * 2];
#pragma unroll
            for (int kh = 0; kh < 7; ++kh) {
                const float v0 = trow[kh * 8], v1 = trow[kh * 8 + 1];
                const float* wk = wp + (kd * 7 + kh) * 8;
#pragma unroll
                for (int oc = 0; oc < 8; ++oc) {
                    const float w = wk[oc];
                    acc[oc][0] = fmaf(w, v0, acc[oc][0]);
                    acc[oc][1] = fmaf(w, v1, acc[oc][1]);
                }
            }
        }
    }

    const int pi = py0 + pl, pjg = px0 + pj;
    const bool doStore = (cp == 0) && (pi < 61) && (pjg < 61);
#pragma unroll
    for (int oc = 0; oc < 8; ++oc) {
        const float bb = b1[oc];
        float a0 = acc[oc][0], a1 = acc[oc][1];
        a0 = fmaxf(a0, __shfl_xor(a0, 4)); a0 = fmaxf(a0, __shfl_xor(a0, 8));
        a1 = fmaxf(a1, __shfl_xor(a1, 4)); a1 = fmaxf(a1, __shfl_xor(a1, 8));
        if (doStore) {
            float2 st = make_float2(fmaxf(a0 + bb, 0.f), fmaxf(a1 + bb, 0.f));
            *reinterpret_cast<float2*>(h1 + ((((size_t)b * 8 + oc) * 61 + pi) * 61 + pjg) * 8 + wq * 2) = st;
        }
    }
}

// ---------------- K2: conv2 5x5 (8->10) + maxpool 2x2 + bias + relu ----------------
// h1:(8,8,61,61,8) -> h2:(8,10,28,28,8).  Tile: 2x4 pooled.  thread=(pos8,quad4,w8)
__global__ __launch_bounds__(256, 8) void k_conv2(const float* __restrict__ h1,
                                                  const float* __restrict__ wt2,
                                                  const float* __restrict__ b2,
                                                  float* __restrict__ h2) {
    const int b = blockIdx.y;
    const int ty = blockIdx.x / 7, tx = blockIdx.x % 7;    // 14 x 7 tiles
    const int py0 = ty * 2, px0 = tx * 4;
    const int iy0 = py0 * 2, ix0 = px0 * 2;

    __shared__ float tin[8 * 12 * 8];    // 3072 B

    const int tid = threadIdx.x;
    const int w = tid & 7;
    const int cp = (tid >> 3) & 3;
    const int pp = tid >> 5;             // 0..7 (2x4)
    const int pl = pp >> 2, pj = pp & 3;
    const int cy = 2 * pl + (cp >> 1), cx = 2 * pj + (cp & 1);

    float acc[10];
#pragma unroll
    for (int oc = 0; oc < 10; ++oc) acc[oc] = 0.f;

    for (int ic = 0; ic < 8; ++ic) {
        __syncthreads();
        const float* hb = h1 + (size_t)(b * 8 + ic) * 29768;   // 61*61*8
        for (int idx = tid; idx < 192; idx += 256) {           // 8 rows * 24 float4 (in-bounds)
            int r = idx / 24, c4 = idx % 24;
            float4 v = *reinterpret_cast<const float4*>(
                hb + ((size_t)(iy0 + r) * 61 + ix0 + (c4 >> 1)) * 8 + (c4 & 1) * 4);
            *reinterpret_cast<float4*>(&tin[idx * 4]) = v;
        }
        __syncthreads();
        const float* wp = wt2 + ic * 25 * 12;
        for (int kd = 0; kd < 5; ++kd) {
            const float* trow = &tin[((cy + kd) * 12 + cx) * 8 + w];
#pragma unroll
            for (int kh = 0; kh < 5; ++kh) {
                const float v = trow[kh * 8];
                const float* wk = wp + (kd * 5 + kh) * 12;
#pragma unroll
                for (int oc = 0; oc < 10; ++oc)
                    acc[oc] = fmaf(wk[oc], v, acc[oc]);
            }
        }
    }

    const int pi = py0 + pl, pjg = px0 + pj;   // always < 28
    const bool doStore = (cp == 0);
#pragma unroll
    for (int oc = 0; oc < 10; ++oc) {
        const float bb = b2[oc];
        float a = acc[oc];
        a = fmaxf(a, __shfl_xor(a, 8)); a = fmaxf(a, __shfl_xor(a, 16));
        if (doStore)
            h2[((((size_t)b * 10 + oc) * 28 + pi) * 28 + pjg) * 8 + w] = fmaxf(a + bb, 0.f);
    }
}

// ---------------- K3: fc1 (62720 -> 32), split-K, all 8 batches per block ----------------
// grid: 32 j * 16 kchunks.  atomicAdd partials into fo[b*32+j] (zeroed by k_prep).
__global__ __launch_bounds__(256) void k_fc1(const float* __restrict__ feat,
                                             const float* __restrict__ w,
                                             float* __restrict__ fo) {
    const int j = blockIdx.x >> 4;
    const int kc = blockIdx.x & 15;
    const int k0 = kc * 3920;
    const float4* w4 = reinterpret_cast<const float4*>(w + (size_t)j * 62720 + k0);
    float acc[8];
#pragma unroll
    for (int b = 0; b < 8; ++b) acc[b] = 0.f;
    for (int i = threadIdx.x; i < 980; i += 256) {
        const float4 wv = w4[i];
#pragma unroll
        for (int b = 0; b < 8; ++b) {
            const float4 fv = *reinterpret_cast<const float4*>(feat + (size_t)b * 62720 + k0 + i * 4);
            acc[b] = fmaf(wv.x, fv.x, fmaf(wv.y, fv.y, fmaf(wv.z, fv.z, fmaf(wv.w, fv.w, acc[b]))));
        }
    }
#pragma unroll
    for (int b = 0; b < 8; ++b)
#pragma unroll
        for (int off = 32; off > 0; off >>= 1) acc[b] += __shfl_down(acc[b], off);
    __shared__ float red[4][8];
    const int wave = threadIdx.x >> 6;
    if ((threadIdx.x & 63) == 0)
#pragma unroll
        for (int b = 0; b < 8; ++b) red[wave][b] = acc[b];
    __syncthreads();
    if (threadIdx.x < 8) {
        float s = red[0][threadIdx.x] + red[1][threadIdx.x] + red[2][threadIdx.x] + red[3][threadIdx.x];
        atomicAdd(&fo[threadIdx.x * 32 + j], s);
    }
}

// ---------------- K4: fc1-bias+relu + fc2 + tanh + rigid transform + moved/reg ----------
// rt[(b*8+t)*8] = {R00,R10,R20,T0, R01,R11,R21,T1}
__global__ __launch_bounds__(1024) void k_fc2_moved(const float* __restrict__ fo,
                                                    const float* __restrict__ f1b,
                                                    const float* __restrict__ w,
                                                    const float* __restrict__ bias,
                                                    const float* __restrict__ pos,
                                                    const float* __restrict__ centers,
                                                    float* __restrict__ rt,
                                                    float* __restrict__ movedOut,
                                                    float* __restrict__ regOut) {
    __shared__ float srt[64 * 8];
    __shared__ float red[8][128];
    const int tid = threadIdx.x;
    if (tid < 64) {
        const int b = tid >> 3, t = tid & 7;
        float f[32];
#pragma unroll
        for (int k = 0; k < 32; ++k) f[k] = fmaxf(fo[b * 32 + k] + f1b[k], 0.f);
        float th[6];
#pragma unroll
        for (int i = 0; i < 6; ++i) {
            const int o = t * 6 + i;
            float s = bias[o];
            const float* wr = w + o * 32;
#pragma unroll
            for (int k = 0; k < 32; ++k) s = fmaf(f[k], wr[k], s);
            th[i] = tanhf(s);
        }
        float s0, c0, s1, c1, s2, c2;
        sincosf(PI_F * th[0], &s0, &c0);
        sincosf(PI_F * th[1], &s1, &c1);
        sincosf(PI_F * th[2], &s2, &c2);
        const float R00 = c0 * c1, R10 = s0 * c1, R20 = -s1;
        const float R01 = -s0 * c2 + c0 * s1 * s2;
        const float R11 =  c0 * c2 + s0 * s1 * s2;
        const float R21 =  c1 * s2;
        const float T0 = th[3] * 128.f + 64.f - (64.f * R00 + 64.f * R10 + 4.f * R20);
        const float T1 = th[4] * 128.f + 64.f - (64.f * R01 + 64.f * R11 + 4.f * R21);
        float* o = srt + tid * 8;
        o[0] = R00; o[1] = R10; o[2] = R20; o[3] = T0;
        o[4] = R01; o[5] = R11; o[6] = R21; o[7] = T1;
        float* og = rt + tid * 8;
        og[0] = R00; og[1] = R10; og[2] = R20; og[3] = T0;
        og[4] = R01; og[5] = R11; og[6] = R21; og[7] = T1;
    }
    __syncthreads();
    const int b = tid >> 7, p = tid & 127;
    float nrm = 0.f;
    if (p < 100) {
        const float* pp = pos + ((size_t)b * 100 + p) * 3;
        const float p0 = pp[0], p1 = pp[1], p2 = pp[2];
        int i0 = (int)rintf(p0); i0 = i0 < 0 ? 0 : (i0 > 127 ? 127 : i0);
        int i1 = (int)rintf(p1); i1 = i1 < 0 ? 0 : (i1 > 127 ? 127 : i1);
        int i2 = (int)rintf(p2); i2 = i2 < 0 ? 0 : (i2 > 7 ? 7 : i2);
        const float gi = (float)i0, gj = (float)i1, gk = (float)i2;
        const float tsx[8] = {32.f, 32.f, 96.f, 96.f, 32.f, 96.f, 64.f, 64.f};
        const float tsy[8] = {32.f, 96.f, 32.f, 96.f, 64.f, 64.f, 32.f, 96.f};
        float u0 = 0.f, u1 = 0.f, es = 0.f;
#pragma unroll
        for (int t = 0; t < 8; ++t) {
            float dx = gi - tsx[t], dy = gj - tsy[t], dz = gk - 4.f;
            float d = sqrtf(dx * dx + dy * dy + dz * dz);
            float e = expf(-d / 10.f);
            const float* r = srt + (b * 8 + t) * 8;
            float f0 = fmaf(gi, r[0], fmaf(gj, r[1], fmaf(gk, r[2], r[3])));
            float f1 = fmaf(gi, r[4], fmaf(gj, r[5], fmaf(gk, r[6], r[7])));
            u0 = fmaf(e, f0, u0);
            u1 = fmaf(e, f1, u1);
            es += e;
        }
        const float inv = 1.f / es;
        const float nf0 = (u0 * inv) * (1.f / 64.f) - 1.f;
        const float nf1 = (u1 * inv) * (1.f / 64.f) - 1.f;
        const float m0 = 2.f * p0 - (0.5f + 0.5f * nf0) * 127.f;
        const float m1 = 2.f * p1 - (0.5f + 0.5f * nf1) * 127.f;
        const float m2 = 2.f * p2 - 3.5f;
        float* mo = movedOut + ((size_t)b * 100 + p) * 3;
        mo[0] = m0; mo[1] = m1; mo[2] = m2;
        const float* ce = centers + p * 3;
        const float d0 = m0 - ce[0], d1 = m1 - ce[1], d2 = m2 - ce[2];
        nrm = sqrtf(d0 * d0 + d1 * d1 + d2 * d2);
    }
    red[b][p] = nrm;
    __syncthreads();
    for (int s = 64; s > 0; s >>= 1) {
        if (p < s) red[b][p] += red[b][p + s];
        __syncthreads();
    }
    if (p == 0) regOut[b] = red[b][0] * 0.01f;
}

// ---------------- K5: flow field + grid output + trilinear grid-sample (fused) ----------
__global__ __launch_bounds__(256) void k_flow_sample(const float* __restrict__ x,
                                                     const float* __restrict__ rt,
                                                     float* __restrict__ outXt,
                                                     float* __restrict__ outGrid) {
    const int b = blockIdx.y;
    const int l = blockIdx.x * 256 + threadIdx.x;   // voxel index, 131072 per batch
    __shared__ float srt[64];
    if (threadIdx.x < 64) srt[threadIdx.x] = rt[b * 64 + threadIdx.x];
    __syncthreads();

    const float gi = (float)(l >> 10);
    const float gj = (float)((l >> 3) & 127);
    const float gk = (float)(l & 7);

    const float tsx[8] = {32.f, 32.f, 96.f, 96.f, 32.f, 96.f, 64.f, 64.f};
    const float tsy[8] = {32.f, 96.f, 32.f, 96.f, 64.f, 64.f, 32.f, 96.f};

    float u0 = 0.f, u1 = 0.f, es = 0.f;
#pragma unroll
    for (int t = 0; t < 8; ++t) {
        float dx = gi - tsx[t], dy = gj - tsy[t], dz = gk - 4.f;
        float d = sqrtf(dx * dx + dy * dy + dz * dz);
        float e = expf(-d / 10.f);
        const float4 ra = *reinterpret_cast<const float4*>(&srt[t * 8]);
        const float4 rb = *reinterpret_cast<const float4*>(&srt[t * 8 + 4]);
        float f0 = fmaf(gi, ra.x, fmaf(gj, ra.y, fmaf(gk, ra.z, ra.w)));
        float f1 = fmaf(gi, rb.x, fmaf(gj, rb.y, fmaf(gk, rb.z, rb.w)));
        u0 = fmaf(e, f0, u0);
        u1 = fmaf(e, f1, u1);
        es += e;
    }
    const float inv = 1.f / es;
    const float fs0 = u0 * inv, fs1 = u1 * inv;
    const float nf0 = fs0 * (1.f / 64.f) - 1.f;
    const float nf1 = fs1 * (1.f / 64.f) - 1.f;

    float* g = outGrid + ((size_t)b * 131072 + l) * 3;
    g[0] = 0.f; g[1] = nf1; g[2] = nf0;

    const float iz = fs0 - 0.5f, iy = fs1 - 0.5f;
    const float z0f = floorf(iz), y0f = floorf(iy);
    const float fz = iz - z0f, fy = iy - y0f;
    const int z0 = (int)z0f, y0 = (int)y0f;
    float s0 = 0.f, s1 = 0.f, s2 = 0.f, s3 = 0.f;
    const float* xb = x + (size_t)b * 4 * 131072;
#pragma unroll
    for (int dz = 0; dz < 2; ++dz) {
        const int zc = z0 + dz;
        if (zc < 0 || zc > 127) continue;
        const float wz = dz ? fz : 1.f - fz;
#pragma unroll
        for (int dy = 0; dy < 2; ++dy) {
            const int yc = y0 + dy;
            if (yc < 0 || yc > 127) continue;
            const float wv = wz * (dy ? fy : 1.f - fy) * 0.5f;
            const float* p = xb + ((size_t)zc * 128 + yc) * 8 + 3;
            s0 = fmaf(wv, p[0] + p[1], s0);
            s1 = fmaf(wv, p[131072] + p[131073], s1);
            s2 = fmaf(wv, p[262144] + p[262145], s2);
            s3 = fmaf(wv, p[393216] + p[393217], s3);
        }
    }
    float* o = outXt + (size_t)b * 4 * 131072 + l;
    o[0] = s0; o[131072] = s1; o[262144] = s2; o[393216] = s3;
}

// ---------------- launch ----------------
extern "C" void kernel_launch(void* const* d_in, const int* in_sizes, int n_in,
                              void* d_out, int out_size, void* d_ws, size_t ws_size,
                              hipStream_t stream) {
    const float* x       = (const float*)d_in[0];
    const float* pos     = (const float*)d_in[1];
    const float* centers = (const float*)d_in[2];
    const float* c1w     = (const float*)d_in[3];
    const float* c1b     = (const float*)d_in[4];
    const float* c2w     = (const float*)d_in[5];
    const float* c2b     = (const float*)d_in[6];
    const float* f1w     = (const float*)d_in[7];
    const float* f1b     = (const float*)d_in[8];
    const float* f2w     = (const float*)d_in[9];
    const float* f2b     = (const float*)d_in[10];

    float* out = (float*)d_out;
    float* ws  = (float*)d_ws;

    // workspace layout (floats)
    float* h1 = ws;                      // 8*8*61*61*8   = 1,905,152
    float* h2 = h1 + 1905152;            // 8*10*28*28*8  =   501,760
    float* fo = h2 + 501760;             // 8*32          =       256
    float* rt = fo + 256;                // 8*8*8         =       512

    // output layout (floats): X_t | grid | reg | moved
    float* outXt    = out;                         // 4,194,304
    float* outGrid  = out + 4194304;               // 3,145,728
    float* outReg   = out + 4194304 + 3145728;     // 8
    float* outMoved = outReg + 8;                  // 2,400

    // weight stash in the tail of outGrid — fully overwritten by k_flow_sample afterwards
    float* stash = out + 4194304 + 3145728 - 4096;
    float* wt1 = stash;                  // 1568
    float* wt2 = stash + 1568;           // 2400

    k_prep<<<1, 256, 0, stream>>>(c1w, c2w, wt1, wt2, fo);
    k_conv1<<<dim3(256, 8), 256, 0, stream>>>(x, wt1, c1b, h1);
    k_conv2<<<dim3(98, 8), 256, 0, stream>>>(h1, wt2, c2b, h2);
    k_fc1<<<512, 256, 0, stream>>>(h2, f1w, fo);
    k_fc2_moved<<<1, 1024, 0, stream>>>(fo, f1b, f2w, f2b, pos, centers, rt, outMoved, outReg);
    k_flow_sample<<<dim3(512, 8), 256, 0, stream>>>(x, rt, outXt, outGrid);
}

// Round 3
// 115.918 us; speedup vs baseline: 1.2096x; 1.1119x over previous
//
#include <hip/hip_runtime.h>

#define PI_F 3.14159265358979323846f

// ---------------- K1: conv1 7x7 (4->8) + maxpool 2x2 + bias + relu ----------------
// x:(8,4,128,128,8) -> h1:(8,8,61,61,8).
// Tile: 8x4 pooled. thread = (pos32, cp4, wq2[4w]). acc[8oc][4w].
// Weights transposed into LDS [ic][tap][oc]; inner-loop w-reads are wave-broadcast b128.
__global__ __launch_bounds__(256, 4) void k_conv1(const float* __restrict__ x,
                                                  const float* __restrict__ w1,
                                                  const float* __restrict__ b1,
                                                  float* __restrict__ h1) {
    const int b = blockIdx.y;
    const int ty = blockIdx.x >> 4, tx = blockIdx.x & 15;   // 8 x 16 tiles
    const int py0 = ty * 8, px0 = tx * 4;
    const int iy0 = py0 * 2, ix0 = px0 * 2;

    __shared__ float tin[22 * 14 * 8];     // 9856 B
    __shared__ float wl[4 * 49 * 8];       // 6272 B  [ic][tap][oc]

    const int tid = threadIdx.x;
    // transpose w1 (oc,ic,tap) -> wl[ic][tap][oc]
    for (int i = tid; i < 1568; i += 256) {
        const int oc = i / 196, rem = i % 196;        // rem = ic*49+tap
        wl[rem * 8 + oc] = w1[i];
    }

    const int wq = tid & 1;                // 4 w each
    const int cp = (tid >> 1) & 3;         // conv pos in 2x2 pool window
    const int pp = tid >> 3;               // 0..31 (8 rows x 4 cols pooled)
    const int pl = pp >> 2, pj = pp & 3;
    const int cy = 2 * pl + (cp >> 1), cx = 2 * pj + (cp & 1);

    float acc[8][4];
#pragma unroll
    for (int oc = 0; oc < 8; ++oc)
#pragma unroll
        for (int w = 0; w < 4; ++w) acc[oc][w] = 0.f;

    for (int ic = 0; ic < 4; ++ic) {
        __syncthreads();
        const float* xb = x + (size_t)(b * 4 + ic) * 131072;
        for (int idx = tid; idx < 616; idx += 256) {   // 22 rows * 28 float4
            const int r = idx / 28, c4 = idx % 28;
            const int row = iy0 + r, col = ix0 + (c4 >> 1);
            float4 v = make_float4(0.f, 0.f, 0.f, 0.f);
            if (row < 128 && col < 128)
                v = *reinterpret_cast<const float4*>(xb + ((size_t)row * 128 + col) * 8 + (c4 & 1) * 4);
            *reinterpret_cast<float4*>(&tin[idx * 4]) = v;
        }
        __syncthreads();
        for (int kd = 0; kd < 7; ++kd) {
            const float* vrow = &tin[((cy + kd) * 14 + cx) * 8 + wq * 4];
            const float* wrow = &wl[(ic * 49 + kd * 7) * 8];
#pragma unroll
            for (int kh = 0; kh < 7; ++kh) {
                const float4 v  = *reinterpret_cast<const float4*>(&vrow[kh * 8]);
                const float4 wa = *reinterpret_cast<const float4*>(&wrow[kh * 8]);
                const float4 wb = *reinterpret_cast<const float4*>(&wrow[kh * 8 + 4]);
                const float ww[8] = {wa.x, wa.y, wa.z, wa.w, wb.x, wb.y, wb.z, wb.w};
                const float vv[4] = {v.x, v.y, v.z, v.w};
#pragma unroll
                for (int oc = 0; oc < 8; ++oc)
#pragma unroll
                    for (int w = 0; w < 4; ++w)
                        acc[oc][w] = fmaf(ww[oc], vv[w], acc[oc][w]);
            }
        }
    }

    const int pi = py0 + pl, pjg = px0 + pj;
    const bool doStore = (cp == 0) && (pi < 61) && (pjg < 61);
#pragma unroll
    for (int oc = 0; oc < 8; ++oc) {
        const float bb = b1[oc];
        float v0 = acc[oc][0], v1 = acc[oc][1], v2 = acc[oc][2], v3 = acc[oc][3];
        v0 = fmaxf(v0, __shfl_xor(v0, 2)); v0 = fmaxf(v0, __shfl_xor(v0, 4));
        v1 = fmaxf(v1, __shfl_xor(v1, 2)); v1 = fmaxf(v1, __shfl_xor(v1, 4));
        v2 = fmaxf(v2, __shfl_xor(v2, 2)); v2 = fmaxf(v2, __shfl_xor(v2, 4));
        v3 = fmaxf(v3, __shfl_xor(v3, 2)); v3 = fmaxf(v3, __shfl_xor(v3, 4));
        if (doStore) {
            float4 st = make_float4(fmaxf(v0 + bb, 0.f), fmaxf(v1 + bb, 0.f),
                                    fmaxf(v2 + bb, 0.f), fmaxf(v3 + bb, 0.f));
            *reinterpret_cast<float4*>(
                h1 + ((((size_t)b * 8 + oc) * 61 + pi) * 61 + pjg) * 8 + wq * 4) = st;
        }
    }
}

// ---------------- K2: conv2 5x5 (8->10) + maxpool 2x2 + bias + relu ----------------
// h1:(8,8,61,61,8) -> h2:(8,10,28,28,8).
// Tile: 2x4 pooled. thread = (pos8, cp4, w8). acc[10]. Weights in LDS (broadcast reads).
__global__ __launch_bounds__(256, 4) void k_conv2(const float* __restrict__ h1,
                                                  const float* __restrict__ w2,
                                                  const float* __restrict__ b2,
                                                  float* __restrict__ h2) {
    const int b = blockIdx.y;
    const int ty = blockIdx.x / 7, tx = blockIdx.x % 7;    // 14 x 7 tiles
    const int py0 = ty * 2, px0 = tx * 4;
    const int iy0 = py0 * 2, ix0 = px0 * 2;

    __shared__ float tin[8 * 12 * 8];      // 3072 B
    __shared__ float wl[8 * 25 * 12];      // 9600 B  [ic][tap][oc pad 12]

    const int tid = threadIdx.x;
    for (int i = tid; i < 2400; i += 256) wl[i] = 0.f;
    __syncthreads();
    for (int i = tid; i < 2000; i += 256) {
        const int oc = i / 200, rem = i % 200;   // rem = ic*25+tap
        wl[rem * 12 + oc] = w2[i];
    }

    const int w  = tid & 7;
    const int cp = (tid >> 3) & 3;
    const int pp = tid >> 5;               // 0..7 (2 rows x 4 cols pooled)
    const int pl = pp >> 2, pj = pp & 3;
    const int cy = 2 * pl + (cp >> 1), cx = 2 * pj + (cp & 1);

    float acc[10];
#pragma unroll
    for (int oc = 0; oc < 10; ++oc) acc[oc] = 0.f;

    for (int ic = 0; ic < 8; ++ic) {
        __syncthreads();
        const float* hb = h1 + (size_t)(b * 8 + ic) * 29768;   // 61*61*8
        for (int idx = tid; idx < 192; idx += 256) {           // 8 rows * 24 float4
            const int r = idx / 24, c4 = idx % 24;
            const float4 v = *reinterpret_cast<const float4*>(
                hb + ((size_t)(iy0 + r) * 61 + ix0 + (c4 >> 1)) * 8 + (c4 & 1) * 4);
            *reinterpret_cast<float4*>(&tin[idx * 4]) = v;
        }
        __syncthreads();
        for (int kd = 0; kd < 5; ++kd) {
            const float* vrow = &tin[((cy + kd) * 12 + cx) * 8 + w];
            const float* wrow = &wl[(ic * 25 + kd * 5) * 12];
#pragma unroll
            for (int kh = 0; kh < 5; ++kh) {
                const float v = vrow[kh * 8];
                const float4 wa = *reinterpret_cast<const float4*>(&wrow[kh * 12]);
                const float4 wb = *reinterpret_cast<const float4*>(&wrow[kh * 12 + 4]);
                const float2 wc = *reinterpret_cast<const float2*>(&wrow[kh * 12 + 8]);
                const float ww[10] = {wa.x, wa.y, wa.z, wa.w, wb.x, wb.y, wb.z, wb.w, wc.x, wc.y};
#pragma unroll
                for (int oc = 0; oc < 10; ++oc)
                    acc[oc] = fmaf(ww[oc], v, acc[oc]);
            }
        }
    }

    const int pi = py0 + pl, pjg = px0 + pj;   // always < 28
    const bool doStore = (cp == 0);
#pragma unroll
    for (int oc = 0; oc < 10; ++oc) {
        const float bb = b2[oc];
        float a = acc[oc];
        a = fmaxf(a, __shfl_xor(a, 8)); a = fmaxf(a, __shfl_xor(a, 16));
        if (doStore)
            h2[((((size_t)b * 10 + oc) * 28 + pi) * 28 + pjg) * 8 + w] = fmaxf(a + bb, 0.f);
    }
}

// ---------------- K3: fc1 (62720 -> 32), split-K, partials to ws ----------------
// grid: 32 j * 16 kchunks. partials[(j*16+kc)*8 + b].
__global__ __launch_bounds__(256) void k_fc1(const float* __restrict__ feat,
                                             const float* __restrict__ w,
                                             float* __restrict__ partials) {
    const int j = blockIdx.x >> 4;
    const int kc = blockIdx.x & 15;
    const int k0 = kc * 3920;
    const float4* w4 = reinterpret_cast<const float4*>(w + (size_t)j * 62720 + k0);
    float acc[8];
#pragma unroll
    for (int b = 0; b < 8; ++b) acc[b] = 0.f;
    for (int i = threadIdx.x; i < 980; i += 256) {
        const float4 wv = w4[i];
#pragma unroll
        for (int b = 0; b < 8; ++b) {
            const float4 fv = *reinterpret_cast<const float4*>(feat + (size_t)b * 62720 + k0 + i * 4);
            acc[b] = fmaf(wv.x, fv.x, fmaf(wv.y, fv.y, fmaf(wv.z, fv.z, fmaf(wv.w, fv.w, acc[b]))));
        }
    }
#pragma unroll
    for (int b = 0; b < 8; ++b)
#pragma unroll
        for (int off = 32; off > 0; off >>= 1) acc[b] += __shfl_down(acc[b], off);
    __shared__ float red[4][8];
    const int wave = threadIdx.x >> 6;
    if ((threadIdx.x & 63) == 0)
#pragma unroll
        for (int b = 0; b < 8; ++b) red[wave][b] = acc[b];
    __syncthreads();
    if (threadIdx.x < 8) {
        partials[(j * 16 + kc) * 8 + threadIdx.x] =
            red[0][threadIdx.x] + red[1][threadIdx.x] + red[2][threadIdx.x] + red[3][threadIdx.x];
    }
}

// ---------------- K4: fc1-reduce + bias/relu + fc2 + tanh + rigid + moved/reg ----------
__global__ __launch_bounds__(1024) void k_fc2_moved(const float* __restrict__ partials,
                                                    const float* __restrict__ f1b,
                                                    const float* __restrict__ w,
                                                    const float* __restrict__ bias,
                                                    const float* __restrict__ pos,
                                                    const float* __restrict__ centers,
                                                    float* __restrict__ rt,
                                                    float* __restrict__ movedOut,
                                                    float* __restrict__ regOut) {
    __shared__ float sfo[256];
    __shared__ float srt[64 * 8];
    __shared__ float red[8][128];
    const int tid = threadIdx.x;
    if (tid < 256) {
        const int b = tid >> 5, j = tid & 31;
        float s = 0.f;
#pragma unroll
        for (int kc = 0; kc < 16; ++kc) s += partials[(j * 16 + kc) * 8 + b];
        sfo[b * 32 + j] = fmaxf(s + f1b[j], 0.f);
    }
    __syncthreads();
    if (tid < 64) {
        const int b = tid >> 3, t = tid & 7;
        const float* f = &sfo[b * 32];
        float th[6];
#pragma unroll
        for (int i = 0; i < 6; ++i) {
            const int o = t * 6 + i;
            float s = bias[o];
            const float* wr = w + o * 32;
#pragma unroll
            for (int k = 0; k < 32; ++k) s = fmaf(f[k], wr[k], s);
            th[i] = tanhf(s);
        }
        float s0, c0, s1, c1, s2, c2;
        sincosf(PI_F * th[0], &s0, &c0);
        sincosf(PI_F * th[1], &s1, &c1);
        sincosf(PI_F * th[2], &s2, &c2);
        const float R00 = c0 * c1, R10 = s0 * c1, R20 = -s1;
        const float R01 = -s0 * c2 + c0 * s1 * s2;
        const float R11 =  c0 * c2 + s0 * s1 * s2;
        const float R21 =  c1 * s2;
        const float T0 = th[3] * 128.f + 64.f - (64.f * R00 + 64.f * R10 + 4.f * R20);
        const float T1 = th[4] * 128.f + 64.f - (64.f * R01 + 64.f * R11 + 4.f * R21);
        float* o = srt + tid * 8;
        o[0] = R00; o[1] = R10; o[2] = R20; o[3] = T0;
        o[4] = R01; o[5] = R11; o[6] = R21; o[7] = T1;
        float* og = rt + tid * 8;
        og[0] = R00; og[1] = R10; og[2] = R20; og[3] = T0;
        og[4] = R01; og[5] = R11; og[6] = R21; og[7] = T1;
    }
    __syncthreads();
    const int b = tid >> 7, p = tid & 127;
    float nrm = 0.f;
    if (p < 100) {
        const float* pp = pos + ((size_t)b * 100 + p) * 3;
        const float p0 = pp[0], p1 = pp[1], p2 = pp[2];
        int i0 = (int)rintf(p0); i0 = i0 < 0 ? 0 : (i0 > 127 ? 127 : i0);
        int i1 = (int)rintf(p1); i1 = i1 < 0 ? 0 : (i1 > 127 ? 127 : i1);
        int i2 = (int)rintf(p2); i2 = i2 < 0 ? 0 : (i2 > 7 ? 7 : i2);
        const float gi = (float)i0, gj = (float)i1, gk = (float)i2;
        const float tsx[8] = {32.f, 32.f, 96.f, 96.f, 32.f, 96.f, 64.f, 64.f};
        const float tsy[8] = {32.f, 96.f, 32.f, 96.f, 64.f, 64.f, 32.f, 96.f};
        float u0 = 0.f, u1 = 0.f, es = 0.f;
#pragma unroll
        for (int t = 0; t < 8; ++t) {
            float dx = gi - tsx[t], dy = gj - tsy[t], dz = gk - 4.f;
            float d = sqrtf(dx * dx + dy * dy + dz * dz);
            float e = expf(-d / 10.f);
            const float* r = srt + (b * 8 + t) * 8;
            float f0 = fmaf(gi, r[0], fmaf(gj, r[1], fmaf(gk, r[2], r[3])));
            float f1 = fmaf(gi, r[4], fmaf(gj, r[5], fmaf(gk, r[6], r[7])));
            u0 = fmaf(e, f0, u0);
            u1 = fmaf(e, f1, u1);
            es += e;
        }
        const float inv = 1.f / es;
        const float nf0 = (u0 * inv) * (1.f / 64.f) - 1.f;
        const float nf1 = (u1 * inv) * (1.f / 64.f) - 1.f;
        const float m0 = 2.f * p0 - (0.5f + 0.5f * nf0) * 127.f;
        const float m1 = 2.f * p1 - (0.5f + 0.5f * nf1) * 127.f;
        const float m2 = 2.f * p2 - 3.5f;
        float* mo = movedOut + ((size_t)b * 100 + p) * 3;
        mo[0] = m0; mo[1] = m1; mo[2] = m2;
        const float* ce = centers + p * 3;
        const float d0 = m0 - ce[0], d1 = m1 - ce[1], d2 = m2 - ce[2];
        nrm = sqrtf(d0 * d0 + d1 * d1 + d2 * d2);
    }
    red[b][p] = nrm;
    __syncthreads();
    for (int s = 64; s > 0; s >>= 1) {
        if (p < s) red[b][p] += red[b][p + s];
        __syncthreads();
    }
    if (p == 0) regOut[b] = red[b][0] * 0.01f;
}

// ---------------- K5: flow field + grid output + trilinear grid-sample (fused) ----------
__global__ __launch_bounds__(256) void k_flow_sample(const float* __restrict__ x,
                                                     const float* __restrict__ rt,
                                                     float* __restrict__ outXt,
                                                     float* __restrict__ outGrid) {
    const int b = blockIdx.y;
    const int l = blockIdx.x * 256 + threadIdx.x;   // voxel index, 131072 per batch
    __shared__ float srt[64];
    if (threadIdx.x < 64) srt[threadIdx.x] = rt[b * 64 + threadIdx.x];
    __syncthreads();

    const float gi = (float)(l >> 10);
    const float gj = (float)((l >> 3) & 127);
    const float gk = (float)(l & 7);

    const float tsx[8] = {32.f, 32.f, 96.f, 96.f, 32.f, 96.f, 64.f, 64.f};
    const float tsy[8] = {32.f, 96.f, 32.f, 96.f, 64.f, 64.f, 32.f, 96.f};

    float u0 = 0.f, u1 = 0.f, es = 0.f;
#pragma unroll
    for (int t = 0; t < 8; ++t) {
        float dx = gi - tsx[t], dy = gj - tsy[t], dz = gk - 4.f;
        float d = sqrtf(dx * dx + dy * dy + dz * dz);
        float e = expf(-d / 10.f);
        const float4 ra = *reinterpret_cast<const float4*>(&srt[t * 8]);
        const float4 rb = *reinterpret_cast<const float4*>(&srt[t * 8 + 4]);
        float f0 = fmaf(gi, ra.x, fmaf(gj, ra.y, fmaf(gk, ra.z, ra.w)));
        float f1 = fmaf(gi, rb.x, fmaf(gj, rb.y, fmaf(gk, rb.z, rb.w)));
        u0 = fmaf(e, f0, u0);
        u1 = fmaf(e, f1, u1);
        es += e;
    }
    const float inv = 1.f / es;
    const float fs0 = u0 * inv, fs1 = u1 * inv;
    const float nf0 = fs0 * (1.f / 64.f) - 1.f;
    const float nf1 = fs1 * (1.f / 64.f) - 1.f;

    float* g = outGrid + ((size_t)b * 131072 + l) * 3;
    g[0] = 0.f; g[1] = nf1; g[2] = nf0;

    const float iz = fs0 - 0.5f, iy = fs1 - 0.5f;
    const float z0f = floorf(iz), y0f = floorf(iy);
    const float fz = iz - z0f, fy = iy - y0f;
    const int z0 = (int)z0f, y0 = (int)y0f;
    float s0 = 0.f, s1 = 0.f, s2 = 0.f, s3 = 0.f;
    const float* xb = x + (size_t)b * 4 * 131072;
#pragma unroll
    for (int dz = 0; dz < 2; ++dz) {
        const int zc = z0 + dz;
        if (zc < 0 || zc > 127) continue;
        const float wz = dz ? fz : 1.f - fz;
#pragma unroll
        for (int dy = 0; dy < 2; ++dy) {
            const int yc = y0 + dy;
            if (yc < 0 || yc > 127) continue;
            const float wv = wz * (dy ? fy : 1.f - fy) * 0.5f;
            const float* p = xb + ((size_t)zc * 128 + yc) * 8 + 3;
            s0 = fmaf(wv, p[0] + p[1], s0);
            s1 = fmaf(wv, p[131072] + p[131073], s1);
            s2 = fmaf(wv, p[262144] + p[262145], s2);
            s3 = fmaf(wv, p[393216] + p[393217], s3);
        }
    }
    float* o = outXt + (size_t)b * 4 * 131072 + l;
    o[0] = s0; o[131072] = s1; o[262144] = s2; o[393216] = s3;
}

// ---------------- launch ----------------
extern "C" void kernel_launch(void* const* d_in, const int* in_sizes, int n_in,
                              void* d_out, int out_size, void* d_ws, size_t ws_size,
                              hipStream_t stream) {
    const float* x       = (const float*)d_in[0];
    const float* pos     = (const float*)d_in[1];
    const float* centers = (const float*)d_in[2];
    const float* c1w     = (const float*)d_in[3];
    const float* c1b     = (const float*)d_in[4];
    const float* c2w     = (const float*)d_in[5];
    const float* c2b     = (const float*)d_in[6];
    const float* f1w     = (const float*)d_in[7];
    const float* f1b     = (const float*)d_in[8];
    const float* f2w     = (const float*)d_in[9];
    const float* f2b     = (const float*)d_in[10];

    float* out = (float*)d_out;
    float* ws  = (float*)d_ws;

    // workspace layout (floats)
    float* h1       = ws;                      // 8*8*61*61*8   = 1,905,152
    float* h2       = h1 + 1905152;            // 8*10*28*28*8  =   501,760
    float* partials = h2 + 501760;             // 32*16*8       =     4,096
    float* rt       = partials + 4096;         // 8*8*8         =       512

    // output layout (floats): X_t | grid | reg | moved
    float* outXt    = out;                         // 4,194,304
    float* outGrid  = out + 4194304;               // 3,145,728
    float* outReg   = out + 4194304 + 3145728;     // 8
    float* outMoved = outReg + 8;                  // 2,400

    k_conv1<<<dim3(128, 8), 256, 0, stream>>>(x, c1w, c1b, h1);
    k_conv2<<<dim3(98, 8), 256, 0, stream>>>(h1, c2w, c2b, h2);
    k_fc1<<<512, 256, 0, stream>>>(h2, f1w, partials);
    k_fc2_moved<<<1, 1024, 0, stream>>>(partials, f1b, f2w, f2b, pos, centers, rt, outMoved, outReg);
    k_flow_sample<<<dim3(512, 8), 256, 0, stream>>>(x, rt, outXt, outGrid);
}